// Round 4
// baseline (408.817 us; speedup 1.0000x reference)
//
#include <hip/hip_runtime.h>

#define NN 50000
#define NE 800000
#define HH 128
#define BN_EPS 1e-5f
#define SCAN_NB ((NN + 255) / 256)   // 196 blocks of 256

typedef unsigned short u16;
typedef unsigned int u32;
typedef short bf16x8 __attribute__((ext_vector_type(8)));
typedef float f32x4 __attribute__((ext_vector_type(4)));

static __device__ __forceinline__ float bf2f(u16 u){
  union { u32 i; float f; } v; v.i = ((u32)u) << 16; return v.f;
}
static __device__ __forceinline__ u16 f2bf(float f){
  union { float f; u32 i; } v; v.f = f;
  u32 x = v.i;
  return (u16)((x + 0x7fffu + ((x >> 16) & 1u)) >> 16);
}
static __device__ __forceinline__ float sigm(float x){
  return 1.f / (1.f + __expf(-x));
}
static __device__ __forceinline__ float tanh_fast(float x){
  return 1.f - 2.f / (1.f + __expf(2.f * x));
}

// ---------------- edge preprocessing ----------------

__global__ void zero_kernel(int* __restrict__ p, int n){
  int i = blockIdx.x * blockDim.x + threadIdx.x;
  if (i < n) p[i] = 0;
}

__global__ void hist_kernel(const int* __restrict__ dst, int* __restrict__ counts, int E){
  int e = blockIdx.x * blockDim.x + threadIdx.x;
  if (e < E) atomicAdd(&counts[dst[e]], 1);
}

// ---- parallel 3-phase exclusive scan ----

__global__ __launch_bounds__(256) void scan_bsum(
    const int* __restrict__ counts, int* __restrict__ bsums, int n){
  int i = blockIdx.x * 256 + threadIdx.x;
  int v = (i < n) ? counts[i] : 0;
#pragma unroll
  for (int off = 1; off < 64; off <<= 1) v += __shfl_xor(v, off);
  __shared__ int ws[4];
  if ((threadIdx.x & 63) == 0) ws[threadIdx.x >> 6] = v;
  __syncthreads();
  if (threadIdx.x == 0) bsums[blockIdx.x] = ws[0] + ws[1] + ws[2] + ws[3];
}

__global__ __launch_bounds__(256) void scan_tops(int* __restrict__ bsums, int nb){
  __shared__ int sh[256];
  int t = threadIdx.x;
  int v = (t < nb) ? bsums[t] : 0;
  sh[t] = v;
  __syncthreads();
  for (int off = 1; off < 256; off <<= 1){
    int u = (t >= off) ? sh[t - off] : 0;
    __syncthreads();
    sh[t] += u;
    __syncthreads();
  }
  if (t < nb) bsums[t] = sh[t] - v;   // exclusive
}

__global__ __launch_bounds__(256) void scan_final(
    const int* __restrict__ counts, const int* __restrict__ bsums,
    int* __restrict__ offs, int* __restrict__ cursor, int n){
  __shared__ int sh[256];
  int t = threadIdx.x;
  int i = blockIdx.x * 256 + t;
  int v = (i < n) ? counts[i] : 0;
  sh[t] = v;
  __syncthreads();
  for (int off = 1; off < 256; off <<= 1){
    int u = (t >= off) ? sh[t - off] : 0;
    __syncthreads();
    sh[t] += u;
    __syncthreads();
  }
  int excl = sh[t] - v + bsums[blockIdx.x];
  if (i < n){ offs[i] = excl; cursor[i] = excl; }
}

// scatter edges into dst-sorted buckets; pack (src, weight) as int2
__global__ void scatter_kernel(const int* __restrict__ src, const int* __restrict__ dst,
                               const float* __restrict__ w, int* __restrict__ cursor,
                               int2* __restrict__ esw, int E){
  int e = blockIdx.x * blockDim.x + threadIdx.x;
  if (e < E){
    int d = dst[e];
    int pos = atomicAdd(&cursor[d], 1);
    esw[pos] = make_int2(src[e], __float_as_int(w[e]));
  }
}

// ---------------- pack weights to bf16 B^T layouts + bias sums ----------------

__global__ void prep_pack(const float* __restrict__ x2hw, const float* __restrict__ h2hw,
                          const float* __restrict__ x2hb, const float* __restrict__ h2hb,
                          const float* __restrict__ gcnw,
                          u16* __restrict__ wcat, u16* __restrict__ wgcn,
                          float* __restrict__ bsum){
  int i = blockIdx.x * blockDim.x + threadIdx.x;   // 131072 threads
  int n = i >> 8, k = i & 255;
  float v = (k < 128) ? x2hw[n * 128 + k] : h2hw[n * 128 + (k - 128)];
  wcat[i] = f2bf(v);
  if (i < 16384){
    int nn = i >> 7, kk = i & 127;
    wgcn[i] = f2bf(gcnw[kk * 128 + nn]);   // transpose [k][n] -> [n][k]
  }
  if (i < 512) bsum[i] = x2hb[i] + h2hb[i];
}

// ---------------- support = x @ gcn_weight via MFMA, global-direct ----------------
__global__ __launch_bounds__(256) void support_mfma(
    const float* __restrict__ x, const u16* __restrict__ wgcn,
    u16* __restrict__ support, int N){
  int tid = threadIdx.x;
  int wave = tid >> 6, lane = tid & 63;
  int c = lane & 15, q = lane >> 4;
  int row0 = blockIdx.x * 64 + wave * 16;
  int arow = row0 + c; if (arow > N - 1) arow = N - 1;   // clamp OOB reads
  f32x4 acc[8];
#pragma unroll
  for (int t = 0; t < 8; t++) acc[t] = (f32x4){0.f, 0.f, 0.f, 0.f};

  const u16* wp = wgcn + (size_t)c * 128 + q * 8;
#pragma unroll
  for (int k0 = 0; k0 < 128; k0 += 32){
    const float* ap = x + (size_t)arow * 128 + k0 + q * 8;
    float4 f0 = *(const float4*)ap;
    float4 f1 = *(const float4*)(ap + 4);
    u16 tmp[8] = {f2bf(f0.x), f2bf(f0.y), f2bf(f0.z), f2bf(f0.w),
                  f2bf(f1.x), f2bf(f1.y), f2bf(f1.z), f2bf(f1.w)};
    bf16x8 afrag = *(bf16x8*)tmp;
#pragma unroll
    for (int t = 0; t < 8; t++){
      bf16x8 bfrag = *(const bf16x8*)(wp + (size_t)t * 16 * 128 + k0);
      acc[t] = __builtin_amdgcn_mfma_f32_16x16x32_bf16(afrag, bfrag, acc[t], 0, 0, 0);
    }
  }
#pragma unroll
  for (int t = 0; t < 8; t++){
#pragma unroll
    for (int j = 0; j < 4; j++){
      int r = row0 + q * 4 + j;
      if (r < N) support[(size_t)r * 128 + t * 16 + c] = f2bf(acc[t][j]);
    }
  }
}

// ---------------- CSR aggregate + relu + bias + BN -> h_bn (bf16) ----------------
// Edge loop manually unrolled 8x: 8 independent gathers in flight per step
// (same fmaf chain order as serial loop -> bit-exact).
__global__ __launch_bounds__(256) void agg_bn2(
    const u16* __restrict__ support, const int2* __restrict__ esw,
    const int* __restrict__ offs, const int* __restrict__ counts,
    const float* __restrict__ bias, const float* __restrict__ gamma,
    const float* __restrict__ beta, const float* __restrict__ mean,
    const float* __restrict__ var, const float* __restrict__ hx,
    u16* __restrict__ hbn, u16* __restrict__ hxb, int N){
  int wid = blockIdx.x * 4 + (threadIdx.x >> 6);
  int lane = threadIdx.x & 63;
  if (wid >= N) return;
  int c = lane * 2;
  // hx row -> bf16 (independent of aggregation; issues early)
  float2 hv = *(const float2*)(hx + (size_t)wid * HH + c);
  int start = offs[wid];
  int deg   = counts[wid];
  float a0 = 0.f, a1 = 0.f;
  for (int base = 0; base < deg; base += 64){
    int cnt = deg - base; if (cnt > 64) cnt = 64;
    int2 my = make_int2(0, 0);
    if (lane < cnt) my = esw[start + base + lane];
    int e = 0;
    for (; e + 8 <= cnt; e += 8){
      int s[8]; float g[8]; u32 u[8];
#pragma unroll
      for (int k = 0; k < 8; k++){
        s[k] = __shfl(my.x, e + k);
        g[k] = __int_as_float(__shfl(my.y, e + k));
      }
#pragma unroll
      for (int k = 0; k < 8; k++)
        u[k] = *(const u32*)(support + (size_t)s[k] * HH + c);
      // same accumulation order as the serial loop (bit-exact)
#pragma unroll
      for (int k = 0; k < 8; k++){
        a0 = fmaf(g[k], bf2f((u16)(u[k] & 0xffffu)), a0);
        a1 = fmaf(g[k], bf2f((u16)(u[k] >> 16)), a1);
      }
    }
    for (; e + 4 <= cnt; e += 4){
      int s[4]; float g[4]; u32 u[4];
#pragma unroll
      for (int k = 0; k < 4; k++){
        s[k] = __shfl(my.x, e + k);
        g[k] = __int_as_float(__shfl(my.y, e + k));
      }
#pragma unroll
      for (int k = 0; k < 4; k++)
        u[k] = *(const u32*)(support + (size_t)s[k] * HH + c);
#pragma unroll
      for (int k = 0; k < 4; k++){
        a0 = fmaf(g[k], bf2f((u16)(u[k] & 0xffffu)), a0);
        a1 = fmaf(g[k], bf2f((u16)(u[k] >> 16)), a1);
      }
    }
    for (; e < cnt; e++){
      int   si = __shfl(my.x, e);
      float gi = __int_as_float(__shfl(my.y, e));
      u32 ui = *(const u32*)(support + (size_t)si * HH + c);
      a0 = fmaf(gi, bf2f((u16)(ui & 0xffffu)), a0);
      a1 = fmaf(gi, bf2f((u16)(ui >> 16)), a1);
    }
  }
  float h0 = fmaxf(a0, 0.f) + bias[c];
  float h1 = fmaxf(a1, 0.f) + bias[c + 1];
  float s0 = gamma[c]     * rsqrtf(var[c]     + BN_EPS);
  float s1 = gamma[c + 1] * rsqrtf(var[c + 1] + BN_EPS);
  float r0 = (h0 - mean[c])     * s0 + beta[c];
  float r1 = (h1 - mean[c + 1]) * s1 + beta[c + 1];
  u32 pack = (u32)f2bf(r0) | ((u32)f2bf(r1) << 16);
  *(u32*)(hbn + (size_t)wid * HH + c) = pack;
  u32 hp = (u32)f2bf(hv.x) | ((u32)f2bf(hv.y) << 16);
  *(u32*)(hxb + (size_t)wid * HH + c) = hp;
}

// ---------------- gates GEMM v3: B in LDS, 4 waves/SIMD ----------------
// Lesson from v2: btile[4][8] (128 VGPR) + acc[4][4] (64 AGPR) > 128 unified
// regs -> HW capped at 2 waves/SIMD. v3 stages B in LDS instead.
// Block = 128 rows x 16 h-cols x all 4 gates. blockIdx.y in [0,8) = h-group.
// B slice: 4 gates x 16 cols x 256 k bf16 = 32 KB LDS, staged once, laid out
// fragment-sequential ((g*8+kk)*64 + lane)*16B -> lane-linear, conflict-free
// ds_read_b128 and conflict-free stage writes.
// 4 waves split rows (32 each): acc[2][4] = 32 AGPR; total regs ~<=112 ->
// 4 waves/SIMD; LDS 32KB -> 4 blocks/CU fits (128 KB).
// grid (128, 8) = 1024 blocks = 4/CU; each block loops ~3 row-chunks so the
// one-time stage amortizes (round-3 lesson: no per-chunk B reload).
__global__ __launch_bounds__(256, 4) void gates_mfma3(
    const u16* __restrict__ hbn, const u16* __restrict__ hxb,
    const u16* __restrict__ wcat, const float* __restrict__ bsum,
    const float* __restrict__ cx, float* __restrict__ out, int N){
  __shared__ bf16x8 lds_b[2048];                 // 32 KB
  int tid = threadIdx.x;
  int wave = tid >> 6, lane = tid & 63;
  int c = lane & 15, q = lane >> 4;
  int hg = blockIdx.y;                           // h-group [0,8)
  int hloc = hg * 16 + c;                        // h in [0,128)

  // ---- stage B slice: 2048 fragments-lanes, 8 iters x 256 threads ----
#pragma unroll
  for (int i = 0; i < 8; i++){
    int idx = i * 256 + tid;                     // [0,2048)
    int f = idx >> 6, l = idx & 63;              // fragment, lane
    int g = f >> 3, kk = f & 7;
    int lq = l >> 4, lc = l & 15;
    const u16* src = wcat + (size_t)(g * 128 + hg * 16 + lc) * 256 + kk * 32 + lq * 8;
    lds_b[idx] = *(const bf16x8*)src;
  }
  __syncthreads();

  float bi  = bsum[hloc];
  float bf_ = bsum[128 + hloc];
  float bg  = bsum[256 + hloc];
  float bo  = bsum[384 + hloc];
  const size_t NH = (size_t)N * HH;

  const int nchunk = (N + 127) >> 7;             // 391
  for (int chunk = blockIdx.x; chunk < nchunk; chunk += gridDim.x){
    int rowbase = chunk * 128 + wave * 32;       // this wave's 32 rows
    f32x4 acc[2][4];
#pragma unroll
    for (int b = 0; b < 2; b++)
#pragma unroll
      for (int g = 0; g < 4; g++) acc[b][g] = (f32x4){0.f, 0.f, 0.f, 0.f};
    int ar0 = rowbase + c;      if (ar0 > N - 1) ar0 = N - 1;
    int ar1 = rowbase + 16 + c; if (ar1 > N - 1) ar1 = N - 1;

#pragma unroll
    for (int kk = 0; kk < 8; kk++){
      const u16* abase = ((kk < 4) ? (hbn + (size_t)(kk * 32))
                                   : (hxb + (size_t)((kk - 4) * 32))) + q * 8;
      bf16x8 a0 = *(const bf16x8*)(abase + (size_t)ar0 * 128);
      bf16x8 a1 = *(const bf16x8*)(abase + (size_t)ar1 * 128);
#pragma unroll
      for (int g = 0; g < 4; g++){
        bf16x8 bfrag = lds_b[(g * 8 + kk) * 64 + lane];
        acc[0][g] = __builtin_amdgcn_mfma_f32_16x16x32_bf16(a0, bfrag, acc[0][g], 0, 0, 0);
        acc[1][g] = __builtin_amdgcn_mfma_f32_16x16x32_bf16(a1, bfrag, acc[1][g], 0, 0, 0);
      }
    }
    // fused LSTM epilogue (all 4 gates register-local per lane)
#pragma unroll
    for (int b = 0; b < 2; b++){
#pragma unroll
      for (int j = 0; j < 4; j++){
        int r = rowbase + b * 16 + q * 4 + j;
        if (r < N){
          float gi = acc[b][0][j] + bi;
          float gf = acc[b][1][j] + bf_;
          float gg = acc[b][2][j] + bg;
          float go = acc[b][3][j] + bo;
          float is = sigm(gi), fs = sigm(gf), gt = tanh_fast(gg), os = sigm(go);
          float co = cx[(size_t)r * HH + hloc];
          float cyv = co * fs + is * gt;
          out[(size_t)r * HH + hloc]      = os * tanh_fast(cyv);
          out[NH + (size_t)r * HH + hloc] = cyv;
        }
      }
    }
  }
}

// ---------------- launch ----------------

extern "C" void kernel_launch(void* const* d_in, const int* in_sizes, int n_in,
                              void* d_out, int out_size, void* d_ws, size_t ws_size,
                              hipStream_t stream){
  const float* x     = (const float*)d_in[0];
  const float* hx    = (const float*)d_in[1];
  const float* cx    = (const float*)d_in[2];
  const int*   esrc  = (const int*)d_in[3];
  const int*   edst  = (const int*)d_in[4];
  const float* ew    = (const float*)d_in[5];
  const float* gcn_w = (const float*)d_in[6];
  const float* bias  = (const float*)d_in[7];
  const float* x2hw  = (const float*)d_in[8];
  const float* x2hb  = (const float*)d_in[9];
  const float* h2hw  = (const float*)d_in[10];
  const float* h2hb  = (const float*)d_in[11];
  const float* bn_g  = (const float*)d_in[12];
  const float* bn_b  = (const float*)d_in[13];
  const float* bn_m  = (const float*)d_in[14];
  const float* bn_v  = (const float*)d_in[15];
  float* out = (float*)d_out;

  char* w = (char*)d_ws;
  u16* support = (u16*)w; w += (((size_t)NN * HH * 2) + 255) & ~(size_t)255;
  u16* hbn     = (u16*)w; w += (((size_t)NN * HH * 2) + 255) & ~(size_t)255;
  u16* hxb     = (u16*)w; w += (((size_t)NN * HH * 2) + 255) & ~(size_t)255;
  int* counts  = (int*)w; w += (((size_t)NN * 4) + 255) & ~(size_t)255;
  int* offs    = (int*)w; w += (((size_t)NN * 4) + 255) & ~(size_t)255;
  int* cursor  = (int*)w; w += (((size_t)NN * 4) + 255) & ~(size_t)255;
  int* bsums   = (int*)w; w += (((size_t)SCAN_NB * 4) + 255) & ~(size_t)255;
  int2* esw    = (int2*)w; w += (((size_t)NE * 8) + 255) & ~(size_t)255;
  u16* wcat    = (u16*)w; w += (((size_t)512 * 256 * 2) + 255) & ~(size_t)255;
  u16* wgcn    = (u16*)w; w += (((size_t)128 * 128 * 2) + 255) & ~(size_t)255;
  float* bsum  = (float*)w; w += (((size_t)512 * 4) + 255) & ~(size_t)255;

  prep_pack<<<512, 256, 0, stream>>>(x2hw, h2hw, x2hb, h2hb, gcn_w, wcat, wgcn, bsum);
  zero_kernel<<<(NN + 255) / 256, 256, 0, stream>>>(counts, NN);
  hist_kernel<<<(NE + 255) / 256, 256, 0, stream>>>(edst, counts, NE);
  scan_bsum<<<SCAN_NB, 256, 0, stream>>>(counts, bsums, NN);
  scan_tops<<<1, 256, 0, stream>>>(bsums, SCAN_NB);
  scan_final<<<SCAN_NB, 256, 0, stream>>>(counts, bsums, offs, cursor, NN);
  scatter_kernel<<<(NE + 255) / 256, 256, 0, stream>>>(esrc, edst, ew, cursor, esw, NE);
  support_mfma<<<(NN + 63) / 64, 256, 0, stream>>>(x, wgcn, support, NN);
  agg_bn2<<<(NN + 3) / 4, 256, 0, stream>>>(support, esw, offs, counts,
                                            bias, bn_g, bn_b, bn_m, bn_v, hx, hbn, hxb, NN);
  gates_mfma3<<<dim3(128, 8), 256, 0, stream>>>(hbn, hxb, wcat, bsum, cx, out, NN);
}

// Round 5
// 404.122 us; speedup vs baseline: 1.0116x; 1.0116x over previous
//
#include <hip/hip_runtime.h>

#define NN 50000
#define NE 800000
#define HH 128
#define BN_EPS 1e-5f
#define SCAN_NB ((NN + 255) / 256)   // 196 blocks of 256

typedef unsigned short u16;
typedef unsigned int u32;
typedef short bf16x8 __attribute__((ext_vector_type(8)));
typedef float f32x4 __attribute__((ext_vector_type(4)));

static __device__ __forceinline__ float bf2f(u16 u){
  union { u32 i; float f; } v; v.i = ((u32)u) << 16; return v.f;
}
static __device__ __forceinline__ u16 f2bf(float f){
  union { float f; u32 i; } v; v.f = f;
  u32 x = v.i;
  return (u16)((x + 0x7fffu + ((x >> 16) & 1u)) >> 16);
}
static __device__ __forceinline__ float sigm(float x){
  return 1.f / (1.f + __expf(-x));
}
static __device__ __forceinline__ float tanh_fast(float x){
  return 1.f - 2.f / (1.f + __expf(2.f * x));
}

// ---------------- edge preprocessing ----------------

__global__ void zero_kernel(int* __restrict__ p, int n){
  int i = blockIdx.x * blockDim.x + threadIdx.x;
  if (i < n) p[i] = 0;
}

__global__ void hist_kernel(const int* __restrict__ dst, int* __restrict__ counts, int E){
  int e = blockIdx.x * blockDim.x + threadIdx.x;
  if (e < E) atomicAdd(&counts[dst[e]], 1);
}

// ---- parallel 3-phase exclusive scan ----

__global__ __launch_bounds__(256) void scan_bsum(
    const int* __restrict__ counts, int* __restrict__ bsums, int n){
  int i = blockIdx.x * 256 + threadIdx.x;
  int v = (i < n) ? counts[i] : 0;
#pragma unroll
  for (int off = 1; off < 64; off <<= 1) v += __shfl_xor(v, off);
  __shared__ int ws[4];
  if ((threadIdx.x & 63) == 0) ws[threadIdx.x >> 6] = v;
  __syncthreads();
  if (threadIdx.x == 0) bsums[blockIdx.x] = ws[0] + ws[1] + ws[2] + ws[3];
}

__global__ __launch_bounds__(256) void scan_tops(int* __restrict__ bsums, int nb){
  __shared__ int sh[256];
  int t = threadIdx.x;
  int v = (t < nb) ? bsums[t] : 0;
  sh[t] = v;
  __syncthreads();
  for (int off = 1; off < 256; off <<= 1){
    int u = (t >= off) ? sh[t - off] : 0;
    __syncthreads();
    sh[t] += u;
    __syncthreads();
  }
  if (t < nb) bsums[t] = sh[t] - v;   // exclusive
}

__global__ __launch_bounds__(256) void scan_final(
    const int* __restrict__ counts, const int* __restrict__ bsums,
    int* __restrict__ offs, int* __restrict__ cursor, int n){
  __shared__ int sh[256];
  int t = threadIdx.x;
  int i = blockIdx.x * 256 + t;
  int v = (i < n) ? counts[i] : 0;
  sh[t] = v;
  __syncthreads();
  for (int off = 1; off < 256; off <<= 1){
    int u = (t >= off) ? sh[t - off] : 0;
    __syncthreads();
    sh[t] += u;
    __syncthreads();
  }
  int excl = sh[t] - v + bsums[blockIdx.x];
  if (i < n){ offs[i] = excl; cursor[i] = excl; }
}

// scatter edges into dst-sorted buckets; pack (src, weight) as int2
__global__ void scatter_kernel(const int* __restrict__ src, const int* __restrict__ dst,
                               const float* __restrict__ w, int* __restrict__ cursor,
                               int2* __restrict__ esw, int E){
  int e = blockIdx.x * blockDim.x + threadIdx.x;
  if (e < E){
    int d = dst[e];
    int pos = atomicAdd(&cursor[d], 1);
    esw[pos] = make_int2(src[e], __float_as_int(w[e]));
  }
}

// ---------------- pack weights to bf16 B^T layouts + bias sums ----------------
// wcat is stored FRAGMENT-SEQUENTIAL: [ntile(32)][kk(8)][lane(64)][e(8)] where
// n = ntile*16 + (lane&15), k = kk*32 + (lane>>4)*8 + e. This makes the gates
// kernel's 128 KB LDS stage a perfectly lane-linear coalesced copy.
__global__ void prep_pack(const float* __restrict__ x2hw, const float* __restrict__ h2hw,
                          const float* __restrict__ x2hb, const float* __restrict__ h2hb,
                          const float* __restrict__ gcnw,
                          u16* __restrict__ wcat, u16* __restrict__ wgcn,
                          float* __restrict__ bsum){
  int i = blockIdx.x * blockDim.x + threadIdx.x;   // 131072 threads
  int n = i >> 8, k = i & 255;
  float v = (k < 128) ? x2hw[n * 128 + k] : h2hw[n * 128 + (k - 128)];
  int nt = n >> 4, lc = n & 15;
  int kk = k >> 5, lq = (k >> 3) & 3, e = k & 7;
  wcat[(((nt * 8 + kk) * 64) + lq * 16 + lc) * 8 + e] = f2bf(v);
  if (i < 16384){
    int nn = i >> 7, kx = i & 127;
    wgcn[i] = f2bf(gcnw[kx * 128 + nn]);   // transpose [k][n] -> [n][k]
  }
  if (i < 512) bsum[i] = x2hb[i] + h2hb[i];
}

// ---------------- support = x @ gcn_weight via MFMA, global-direct ----------------
__global__ __launch_bounds__(256) void support_mfma(
    const float* __restrict__ x, const u16* __restrict__ wgcn,
    u16* __restrict__ support, int N){
  int tid = threadIdx.x;
  int wave = tid >> 6, lane = tid & 63;
  int c = lane & 15, q = lane >> 4;
  int row0 = blockIdx.x * 64 + wave * 16;
  int arow = row0 + c; if (arow > N - 1) arow = N - 1;   // clamp OOB reads
  f32x4 acc[8];
#pragma unroll
  for (int t = 0; t < 8; t++) acc[t] = (f32x4){0.f, 0.f, 0.f, 0.f};

  const u16* wp = wgcn + (size_t)c * 128 + q * 8;
#pragma unroll
  for (int k0 = 0; k0 < 128; k0 += 32){
    const float* ap = x + (size_t)arow * 128 + k0 + q * 8;
    float4 f0 = *(const float4*)ap;
    float4 f1 = *(const float4*)(ap + 4);
    u16 tmp[8] = {f2bf(f0.x), f2bf(f0.y), f2bf(f0.z), f2bf(f0.w),
                  f2bf(f1.x), f2bf(f1.y), f2bf(f1.z), f2bf(f1.w)};
    bf16x8 afrag = *(bf16x8*)tmp;
#pragma unroll
    for (int t = 0; t < 8; t++){
      bf16x8 bfrag = *(const bf16x8*)(wp + (size_t)t * 16 * 128 + k0);
      acc[t] = __builtin_amdgcn_mfma_f32_16x16x32_bf16(afrag, bfrag, acc[t], 0, 0, 0);
    }
  }
#pragma unroll
  for (int t = 0; t < 8; t++){
#pragma unroll
    for (int j = 0; j < 4; j++){
      int r = row0 + q * 4 + j;
      if (r < N) support[(size_t)r * 128 + t * 16 + c] = f2bf(acc[t][j]);
    }
  }
}

// ---------------- CSR aggregate + relu + bias + BN -> h_bn (bf16) ----------------
// Edge loop manually unrolled 8x: 8 independent gathers in flight per step
// (same fmaf chain order as serial loop -> bit-exact).
__global__ __launch_bounds__(256) void agg_bn2(
    const u16* __restrict__ support, const int2* __restrict__ esw,
    const int* __restrict__ offs, const int* __restrict__ counts,
    const float* __restrict__ bias, const float* __restrict__ gamma,
    const float* __restrict__ beta, const float* __restrict__ mean,
    const float* __restrict__ var, const float* __restrict__ hx,
    u16* __restrict__ hbn, u16* __restrict__ hxb, int N){
  int wid = blockIdx.x * 4 + (threadIdx.x >> 6);
  int lane = threadIdx.x & 63;
  if (wid >= N) return;
  int c = lane * 2;
  // hx row -> bf16 (independent of aggregation; issues early)
  float2 hv = *(const float2*)(hx + (size_t)wid * HH + c);
  int start = offs[wid];
  int deg   = counts[wid];
  float a0 = 0.f, a1 = 0.f;
  for (int base = 0; base < deg; base += 64){
    int cnt = deg - base; if (cnt > 64) cnt = 64;
    int2 my = make_int2(0, 0);
    if (lane < cnt) my = esw[start + base + lane];
    int e = 0;
    for (; e + 8 <= cnt; e += 8){
      int s[8]; float g[8]; u32 u[8];
#pragma unroll
      for (int k = 0; k < 8; k++){
        s[k] = __shfl(my.x, e + k);
        g[k] = __int_as_float(__shfl(my.y, e + k));
      }
#pragma unroll
      for (int k = 0; k < 8; k++)
        u[k] = *(const u32*)(support + (size_t)s[k] * HH + c);
      // same accumulation order as the serial loop (bit-exact)
#pragma unroll
      for (int k = 0; k < 8; k++){
        a0 = fmaf(g[k], bf2f((u16)(u[k] & 0xffffu)), a0);
        a1 = fmaf(g[k], bf2f((u16)(u[k] >> 16)), a1);
      }
    }
    for (; e + 4 <= cnt; e += 4){
      int s[4]; float g[4]; u32 u[4];
#pragma unroll
      for (int k = 0; k < 4; k++){
        s[k] = __shfl(my.x, e + k);
        g[k] = __int_as_float(__shfl(my.y, e + k));
      }
#pragma unroll
      for (int k = 0; k < 4; k++)
        u[k] = *(const u32*)(support + (size_t)s[k] * HH + c);
#pragma unroll
      for (int k = 0; k < 4; k++){
        a0 = fmaf(g[k], bf2f((u16)(u[k] & 0xffffu)), a0);
        a1 = fmaf(g[k], bf2f((u16)(u[k] >> 16)), a1);
      }
    }
    for (; e < cnt; e++){
      int   si = __shfl(my.x, e);
      float gi = __int_as_float(__shfl(my.y, e));
      u32 ui = *(const u32*)(support + (size_t)si * HH + c);
      a0 = fmaf(gi, bf2f((u16)(ui & 0xffffu)), a0);
      a1 = fmaf(gi, bf2f((u16)(ui >> 16)), a1);
    }
  }
  float h0 = fmaxf(a0, 0.f) + bias[c];
  float h1 = fmaxf(a1, 0.f) + bias[c + 1];
  float s0 = gamma[c]     * rsqrtf(var[c]     + BN_EPS);
  float s1 = gamma[c + 1] * rsqrtf(var[c + 1] + BN_EPS);
  float r0 = (h0 - mean[c])     * s0 + beta[c];
  float r1 = (h1 - mean[c + 1]) * s1 + beta[c + 1];
  u32 pack = (u32)f2bf(r0) | ((u32)f2bf(r1) << 16);
  *(u32*)(hbn + (size_t)wid * HH + c) = pack;
  u32 hp = (u32)f2bf(hv.x) | ((u32)f2bf(hv.y) << 16);
  *(u32*)(hxb + (size_t)wid * HH + c) = hp;
}

// ---------------- gates GEMM v4: half-B in 128 KB LDS, 1024-thread blocks ----------------
// Lessons: v2 (B in 128 VGPR) -> 2 waves/SIMD reg cap. v3 (8-way h-split) ->
// 8x A re-read (163 MB FETCH) + 64B/row sub-cacheline writes (2.6x WRITE).
// v4: h-split = 2 ONLY. Half of B = 4 gates x 64 h x 256 k bf16 = 128 KB LDS,
// staged once (lane-linear copy from fragment-sequential wcat). 1024 threads =
// 16 waves; LDS caps 1 block/CU -> 16 waves/CU (50%). Wave (rb,cg) = 32 rows x
// 64 cols (4 gates x 16 h); acc[2][4] = 32 regs -> VGPR well under 128.
// A re-read 2x (51 MB), writes 256 B/row contiguous per block (full lines).
// grid (128,2) = 256 blocks = 1/CU; each loops ~3 chunks of 128 rows.
__global__ __launch_bounds__(1024) void gates_mfma4(
    const u16* __restrict__ hbn, const u16* __restrict__ hxb,
    const u16* __restrict__ wcat, const float* __restrict__ bsum,
    const float* __restrict__ cx, float* __restrict__ out, int N){
  __shared__ bf16x8 lds_b[8192];                 // 128 KB
  int tid = threadIdx.x;
  int wave = tid >> 6, lane = tid & 63;
  int c = lane & 15, q = lane >> 4;
  int rb = wave >> 2, cg = wave & 3;             // row-band, col-group
  int hc = blockIdx.y;                           // h-half [0,2)
  int hloc = hc * 64 + cg * 16 + c;              // h in [0,128)

  // ---- stage half-B: 8192 x 16B, fully coalesced (wcat is fragment-sequential)
  const bf16x8* wsrc = (const bf16x8*)wcat;
#pragma unroll
  for (int it = 0; it < 8; it++){
    int idx = it * 1024 + tid;                   // [0,8192)
    int lf = idx >> 6, l = idx & 63;             // local frag, lane slot
    int scg = lf >> 5, sg = (lf >> 3) & 3, skk = lf & 7;
    int nt = sg * 8 + hc * 4 + scg;              // global n-tile [0,32)
    lds_b[idx] = wsrc[(nt * 8 + skk) * 64 + l];
  }
  __syncthreads();

  float bi  = bsum[hloc];
  float bf_ = bsum[128 + hloc];
  float bg  = bsum[256 + hloc];
  float bo  = bsum[384 + hloc];
  const size_t NH = (size_t)N * HH;

  const int nchunk = (N + 127) >> 7;             // 391 chunks of 128 rows
  for (int chunk = blockIdx.x; chunk < nchunk; chunk += gridDim.x){
    int rowbase = chunk * 128 + rb * 32;         // this wave's 32 rows
    f32x4 acc[2][4];
#pragma unroll
    for (int b = 0; b < 2; b++)
#pragma unroll
      for (int g = 0; g < 4; g++) acc[b][g] = (f32x4){0.f, 0.f, 0.f, 0.f};
    int ar0 = rowbase + c;      if (ar0 > N - 1) ar0 = N - 1;
    int ar1 = rowbase + 16 + c; if (ar1 > N - 1) ar1 = N - 1;

#pragma unroll
    for (int kk = 0; kk < 8; kk++){
      const u16* abase = ((kk < 4) ? (hbn + (size_t)(kk * 32))
                                   : (hxb + (size_t)((kk - 4) * 32))) + q * 8;
      bf16x8 a0 = *(const bf16x8*)(abase + (size_t)ar0 * 128);
      bf16x8 a1 = *(const bf16x8*)(abase + (size_t)ar1 * 128);
#pragma unroll
      for (int g = 0; g < 4; g++){
        bf16x8 bfrag = lds_b[((cg * 4 + g) * 8 + kk) * 64 + lane];
        acc[0][g] = __builtin_amdgcn_mfma_f32_16x16x32_bf16(a0, bfrag, acc[0][g], 0, 0, 0);
        acc[1][g] = __builtin_amdgcn_mfma_f32_16x16x32_bf16(a1, bfrag, acc[1][g], 0, 0, 0);
      }
    }
    // fused LSTM epilogue (all 4 gates register-local per lane)
#pragma unroll
    for (int b = 0; b < 2; b++){
#pragma unroll
      for (int j = 0; j < 4; j++){
        int r = rowbase + b * 16 + q * 4 + j;
        if (r < N){
          float gi = acc[b][0][j] + bi;
          float gf = acc[b][1][j] + bf_;
          float gg = acc[b][2][j] + bg;
          float go = acc[b][3][j] + bo;
          float is = sigm(gi), fs = sigm(gf), gt = tanh_fast(gg), os = sigm(go);
          float co = cx[(size_t)r * HH + hloc];
          float cyv = co * fs + is * gt;
          out[(size_t)r * HH + hloc]      = os * tanh_fast(cyv);
          out[NH + (size_t)r * HH + hloc] = cyv;
        }
      }
    }
  }
}

// ---------------- launch ----------------

extern "C" void kernel_launch(void* const* d_in, const int* in_sizes, int n_in,
                              void* d_out, int out_size, void* d_ws, size_t ws_size,
                              hipStream_t stream){
  const float* x     = (const float*)d_in[0];
  const float* hx    = (const float*)d_in[1];
  const float* cx    = (const float*)d_in[2];
  const int*   esrc  = (const int*)d_in[3];
  const int*   edst  = (const int*)d_in[4];
  const float* ew    = (const float*)d_in[5];
  const float* gcn_w = (const float*)d_in[6];
  const float* bias  = (const float*)d_in[7];
  const float* x2hw  = (const float*)d_in[8];
  const float* x2hb  = (const float*)d_in[9];
  const float* h2hw  = (const float*)d_in[10];
  const float* h2hb  = (const float*)d_in[11];
  const float* bn_g  = (const float*)d_in[12];
  const float* bn_b  = (const float*)d_in[13];
  const float* bn_m  = (const float*)d_in[14];
  const float* bn_v  = (const float*)d_in[15];
  float* out = (float*)d_out;

  char* w = (char*)d_ws;
  u16* support = (u16*)w; w += (((size_t)NN * HH * 2) + 255) & ~(size_t)255;
  u16* hbn     = (u16*)w; w += (((size_t)NN * HH * 2) + 255) & ~(size_t)255;
  u16* hxb     = (u16*)w; w += (((size_t)NN * HH * 2) + 255) & ~(size_t)255;
  int* counts  = (int*)w; w += (((size_t)NN * 4) + 255) & ~(size_t)255;
  int* offs    = (int*)w; w += (((size_t)NN * 4) + 255) & ~(size_t)255;
  int* cursor  = (int*)w; w += (((size_t)NN * 4) + 255) & ~(size_t)255;
  int* bsums   = (int*)w; w += (((size_t)SCAN_NB * 4) + 255) & ~(size_t)255;
  int2* esw    = (int2*)w; w += (((size_t)NE * 8) + 255) & ~(size_t)255;
  u16* wcat    = (u16*)w; w += (((size_t)512 * 256 * 2) + 255) & ~(size_t)255;
  u16* wgcn    = (u16*)w; w += (((size_t)128 * 128 * 2) + 255) & ~(size_t)255;
  float* bsum  = (float*)w; w += (((size_t)512 * 4) + 255) & ~(size_t)255;

  prep_pack<<<512, 256, 0, stream>>>(x2hw, h2hw, x2hb, h2hb, gcn_w, wcat, wgcn, bsum);
  zero_kernel<<<(NN + 255) / 256, 256, 0, stream>>>(counts, NN);
  hist_kernel<<<(NE + 255) / 256, 256, 0, stream>>>(edst, counts, NE);
  scan_bsum<<<SCAN_NB, 256, 0, stream>>>(counts, bsums, NN);
  scan_tops<<<1, 256, 0, stream>>>(bsums, SCAN_NB);
  scan_final<<<SCAN_NB, 256, 0, stream>>>(counts, bsums, offs, cursor, NN);
  scatter_kernel<<<(NE + 255) / 256, 256, 0, stream>>>(esrc, edst, ew, cursor, esw, NE);
  support_mfma<<<(NN + 63) / 64, 256, 0, stream>>>(x, wgcn, support, NN);
  agg_bn2<<<(NN + 3) / 4, 256, 0, stream>>>(support, esw, offs, counts,
                                            bias, bn_g, bn_b, bn_m, bn_v, hx, hbn, hxb, NN);
  gates_mfma4<<<dim3(128, 2), 1024, 0, stream>>>(hbn, hxb, wcat, bsum, cx, out, NN);
}

// Round 6
// 350.003 us; speedup vs baseline: 1.1680x; 1.1546x over previous
//
#include <hip/hip_runtime.h>

#define NN 50000
#define NE 800000
#define HH 128
#define BN_EPS 1e-5f
#define SCAN_NB ((NN + 255) / 256)   // 196 blocks of 256

typedef unsigned short u16;
typedef unsigned int u32;
typedef short bf16x8 __attribute__((ext_vector_type(8)));
typedef float f32x4 __attribute__((ext_vector_type(4)));

static __device__ __forceinline__ float bf2f(u16 u){
  union { u32 i; float f; } v; v.i = ((u32)u) << 16; return v.f;
}
static __device__ __forceinline__ u16 f2bf(float f){
  union { float f; u32 i; } v; v.f = f;
  u32 x = v.i;
  return (u16)((x + 0x7fffu + ((x >> 16) & 1u)) >> 16);
}
static __device__ __forceinline__ float sigm(float x){
  return 1.f / (1.f + __expf(-x));
}
static __device__ __forceinline__ float tanh_fast(float x){
  return 1.f - 2.f / (1.f + __expf(2.f * x));
}

// ---------------- edge preprocessing ----------------

__global__ void zero_kernel(int* __restrict__ p, int n){
  int i = blockIdx.x * blockDim.x + threadIdx.x;
  if (i < n) p[i] = 0;
}

__global__ void hist_kernel(const int* __restrict__ dst, int* __restrict__ counts, int E){
  int e = blockIdx.x * blockDim.x + threadIdx.x;
  if (e < E) atomicAdd(&counts[dst[e]], 1);
}

// ---- parallel 3-phase exclusive scan ----

__global__ __launch_bounds__(256) void scan_bsum(
    const int* __restrict__ counts, int* __restrict__ bsums, int n){
  int i = blockIdx.x * 256 + threadIdx.x;
  int v = (i < n) ? counts[i] : 0;
#pragma unroll
  for (int off = 1; off < 64; off <<= 1) v += __shfl_xor(v, off);
  __shared__ int ws[4];
  if ((threadIdx.x & 63) == 0) ws[threadIdx.x >> 6] = v;
  __syncthreads();
  if (threadIdx.x == 0) bsums[blockIdx.x] = ws[0] + ws[1] + ws[2] + ws[3];
}

__global__ __launch_bounds__(256) void scan_tops(int* __restrict__ bsums, int nb){
  __shared__ int sh[256];
  int t = threadIdx.x;
  int v = (t < nb) ? bsums[t] : 0;
  sh[t] = v;
  __syncthreads();
  for (int off = 1; off < 256; off <<= 1){
    int u = (t >= off) ? sh[t - off] : 0;
    __syncthreads();
    sh[t] += u;
    __syncthreads();
  }
  if (t < nb) bsums[t] = sh[t] - v;   // exclusive
}

__global__ __launch_bounds__(256) void scan_final(
    const int* __restrict__ counts, const int* __restrict__ bsums,
    int* __restrict__ offs, int* __restrict__ cursor, int n){
  __shared__ int sh[256];
  int t = threadIdx.x;
  int i = blockIdx.x * 256 + t;
  int v = (i < n) ? counts[i] : 0;
  sh[t] = v;
  __syncthreads();
  for (int off = 1; off < 256; off <<= 1){
    int u = (t >= off) ? sh[t - off] : 0;
    __syncthreads();
    sh[t] += u;
    __syncthreads();
  }
  int excl = sh[t] - v + bsums[blockIdx.x];
  if (i < n){ offs[i] = excl; cursor[i] = excl; }
}

// scatter edges into dst-sorted buckets; pack (src, weight) as int2
__global__ void scatter_kernel(const int* __restrict__ src, const int* __restrict__ dst,
                               const float* __restrict__ w, int* __restrict__ cursor,
                               int2* __restrict__ esw, int E){
  int e = blockIdx.x * blockDim.x + threadIdx.x;
  if (e < E){
    int d = dst[e];
    int pos = atomicAdd(&cursor[d], 1);
    esw[pos] = make_int2(src[e], __float_as_int(w[e]));
  }
}

// ---------------- pack weights to bf16 B^T layouts + bias sums ----------------
// wcat is stored FRAGMENT-SEQUENTIAL: [ntile(32)][kk(8)][lane(64)][e(8)] where
// n = ntile*16 + (lane&15), k = kk*32 + (lane>>4)*8 + e -> one bf16x8 wave-load
// per MFMA B fragment, perfectly lane-linear.
__global__ void prep_pack(const float* __restrict__ x2hw, const float* __restrict__ h2hw,
                          const float* __restrict__ x2hb, const float* __restrict__ h2hb,
                          const float* __restrict__ gcnw,
                          u16* __restrict__ wcat, u16* __restrict__ wgcn,
                          float* __restrict__ bsum){
  int i = blockIdx.x * blockDim.x + threadIdx.x;   // 131072 threads
  int n = i >> 8, k = i & 255;
  float v = (k < 128) ? x2hw[n * 128 + k] : h2hw[n * 128 + (k - 128)];
  int nt = n >> 4, lc = n & 15;
  int kk = k >> 5, lq = (k >> 3) & 3, e = k & 7;
  wcat[(((nt * 8 + kk) * 64) + lq * 16 + lc) * 8 + e] = f2bf(v);
  if (i < 16384){
    int nn = i >> 7, kx = i & 127;
    wgcn[i] = f2bf(gcnw[kx * 128 + nn]);   // transpose [k][n] -> [n][k]
  }
  if (i < 512) bsum[i] = x2hb[i] + h2hb[i];
}

// ---------------- support = x @ gcn_weight via MFMA, global-direct ----------------
__global__ __launch_bounds__(256) void support_mfma(
    const float* __restrict__ x, const u16* __restrict__ wgcn,
    u16* __restrict__ support, int N){
  int tid = threadIdx.x;
  int wave = tid >> 6, lane = tid & 63;
  int c = lane & 15, q = lane >> 4;
  int row0 = blockIdx.x * 64 + wave * 16;
  int arow = row0 + c; if (arow > N - 1) arow = N - 1;   // clamp OOB reads
  f32x4 acc[8];
#pragma unroll
  for (int t = 0; t < 8; t++) acc[t] = (f32x4){0.f, 0.f, 0.f, 0.f};

  const u16* wp = wgcn + (size_t)c * 128 + q * 8;
#pragma unroll
  for (int k0 = 0; k0 < 128; k0 += 32){
    const float* ap = x + (size_t)arow * 128 + k0 + q * 8;
    float4 f0 = *(const float4*)ap;
    float4 f1 = *(const float4*)(ap + 4);
    u16 tmp[8] = {f2bf(f0.x), f2bf(f0.y), f2bf(f0.z), f2bf(f0.w),
                  f2bf(f1.x), f2bf(f1.y), f2bf(f1.z), f2bf(f1.w)};
    bf16x8 afrag = *(bf16x8*)tmp;
#pragma unroll
    for (int t = 0; t < 8; t++){
      bf16x8 bfrag = *(const bf16x8*)(wp + (size_t)t * 16 * 128 + k0);
      acc[t] = __builtin_amdgcn_mfma_f32_16x16x32_bf16(afrag, bfrag, acc[t], 0, 0, 0);
    }
  }
#pragma unroll
  for (int t = 0; t < 8; t++){
#pragma unroll
    for (int j = 0; j < 4; j++){
      int r = row0 + q * 4 + j;
      if (r < N) support[(size_t)r * 128 + t * 16 + c] = f2bf(acc[t][j]);
    }
  }
}

// ---------------- CSR aggregate + relu + bias + BN -> h_bn (bf16) ----------------
// Edge loop manually unrolled 8x: 8 independent gathers in flight per step
// (same fmaf chain order as serial loop -> bit-exact).
__global__ __launch_bounds__(256) void agg_bn2(
    const u16* __restrict__ support, const int2* __restrict__ esw,
    const int* __restrict__ offs, const int* __restrict__ counts,
    const float* __restrict__ bias, const float* __restrict__ gamma,
    const float* __restrict__ beta, const float* __restrict__ mean,
    const float* __restrict__ var, const float* __restrict__ hx,
    u16* __restrict__ hbn, u16* __restrict__ hxb, int N){
  int wid = blockIdx.x * 4 + (threadIdx.x >> 6);
  int lane = threadIdx.x & 63;
  if (wid >= N) return;
  int c = lane * 2;
  // hx row -> bf16 (independent of aggregation; issues early)
  float2 hv = *(const float2*)(hx + (size_t)wid * HH + c);
  int start = offs[wid];
  int deg   = counts[wid];
  float a0 = 0.f, a1 = 0.f;
  for (int base = 0; base < deg; base += 64){
    int cnt = deg - base; if (cnt > 64) cnt = 64;
    int2 my = make_int2(0, 0);
    if (lane < cnt) my = esw[start + base + lane];
    int e = 0;
    for (; e + 8 <= cnt; e += 8){
      int s[8]; float g[8]; u32 u[8];
#pragma unroll
      for (int k = 0; k < 8; k++){
        s[k] = __shfl(my.x, e + k);
        g[k] = __int_as_float(__shfl(my.y, e + k));
      }
#pragma unroll
      for (int k = 0; k < 8; k++)
        u[k] = *(const u32*)(support + (size_t)s[k] * HH + c);
      // same accumulation order as the serial loop (bit-exact)
#pragma unroll
      for (int k = 0; k < 8; k++){
        a0 = fmaf(g[k], bf2f((u16)(u[k] & 0xffffu)), a0);
        a1 = fmaf(g[k], bf2f((u16)(u[k] >> 16)), a1);
      }
    }
    for (; e + 4 <= cnt; e += 4){
      int s[4]; float g[4]; u32 u[4];
#pragma unroll
      for (int k = 0; k < 4; k++){
        s[k] = __shfl(my.x, e + k);
        g[k] = __int_as_float(__shfl(my.y, e + k));
      }
#pragma unroll
      for (int k = 0; k < 4; k++)
        u[k] = *(const u32*)(support + (size_t)s[k] * HH + c);
#pragma unroll
      for (int k = 0; k < 4; k++){
        a0 = fmaf(g[k], bf2f((u16)(u[k] & 0xffffu)), a0);
        a1 = fmaf(g[k], bf2f((u16)(u[k] >> 16)), a1);
      }
    }
    for (; e < cnt; e++){
      int   si = __shfl(my.x, e);
      float gi = __int_as_float(__shfl(my.y, e));
      u32 ui = *(const u32*)(support + (size_t)si * HH + c);
      a0 = fmaf(gi, bf2f((u16)(ui & 0xffffu)), a0);
      a1 = fmaf(gi, bf2f((u16)(ui >> 16)), a1);
    }
  }
  float h0 = fmaxf(a0, 0.f) + bias[c];
  float h1 = fmaxf(a1, 0.f) + bias[c + 1];
  float s0 = gamma[c]     * rsqrtf(var[c]     + BN_EPS);
  float s1 = gamma[c + 1] * rsqrtf(var[c + 1] + BN_EPS);
  float r0 = (h0 - mean[c])     * s0 + beta[c];
  float r1 = (h1 - mean[c + 1]) * s1 + beta[c + 1];
  u32 pack = (u32)f2bf(r0) | ((u32)f2bf(r1) << 16);
  *(u32*)(hbn + (size_t)wid * HH + c) = pack;
  u32 hp = (u32)f2bf(hv.x) | ((u32)f2bf(hv.y) << 16);
  *(u32*)(hxb + (size_t)wid * HH + c) = hp;
}

// ---------------- gates GEMM v5: B in regs, k-split wave pairs ----------------
// Lessons: v2 (B-in-reg, all-k per wave) = 128 B-VGPR -> 2 waves/SIMD cap, but
// best measured (86us). v3/v4 (LDS-B) = 126-131us regardless of geometry.
// v5 keeps B in registers and halves the per-wave footprint by k-splitting:
// wave (kh, cw): kh = k-half (kh=0 reads ONLY hbn, kh=1 ONLY hxb),
// cw = 16 h-cols x all 4 gates. btile[4][4] = 64 VGPR, acc[4] = 16 ->
// ~110 total -> 4 waves/SIMD. Block = 1024 thr = 16 waves = 16 rows x all
// 512 gate-cols x full k: NO h-split -> A read once, out rows written fully.
// k-halves combined via 64 KB double-buffered LDS (lane-linear f32, conflict-
// free), ONE __syncthreads per chunk; kh=0 does the register-local epilogue.
// grid = 256, each block loops 12-13 chunks of 16 rows (3125 = 50000/16 exact,
// so no row guards). B loaded once per block = 65 MB aggregate L2-hit reads.
__global__ __launch_bounds__(1024, 1) void gates_mfma5(
    const u16* __restrict__ hbn, const u16* __restrict__ hxb,
    const u16* __restrict__ wcat, const float* __restrict__ bsum,
    const float* __restrict__ cx, float* __restrict__ out, int N){
  __shared__ float lbuf[2][8][16][64];           // 64 KB, [buf][cw][g*4+j][lane]
  int tid = threadIdx.x;
  int wave = tid >> 6, lane = tid & 63;
  int c = lane & 15, q = lane >> 4;
  int cw = wave & 7, kh = wave >> 3;
  int hloc = cw * 16 + c;                        // h in [0,128)

  // resident B: 4 gates x this wave's k-half (4 kk steps) = 64 VGPR
  const bf16x8* wsrc = (const bf16x8*)wcat;
  bf16x8 btile[4][4];
#pragma unroll
  for (int g = 0; g < 4; g++)
#pragma unroll
    for (int kk = 0; kk < 4; kk++)
      btile[g][kk] = wsrc[((size_t)((g * 8 + cw) * 8) + kh * 4 + kk) * 64 + lane];

  float bi = 0.f, bf_ = 0.f, bg = 0.f, bo = 0.f;
  if (kh == 0){
    bi  = bsum[hloc];
    bf_ = bsum[128 + hloc];
    bg  = bsum[256 + hloc];
    bo  = bsum[384 + hloc];
  }
  const u16* abuf = kh ? hxb : hbn;              // each wave reads ONE A matrix
  const size_t NH = (size_t)N * HH;
  const int nchunk = N >> 4;                     // 3125 (N = 50000 = 3125*16)
  int p = 0;

  for (int chunk = blockIdx.x; chunk < nchunk; chunk += gridDim.x){
    int row0 = chunk << 4;
    f32x4 acc[4];
#pragma unroll
    for (int g = 0; g < 4; g++) acc[g] = (f32x4){0.f, 0.f, 0.f, 0.f};
    const u16* ap = abuf + (size_t)(row0 + c) * 128 + q * 8;
#pragma unroll
    for (int kk = 0; kk < 4; kk++){
      bf16x8 a = *(const bf16x8*)(ap + kk * 32);
#pragma unroll
      for (int g = 0; g < 4; g++)
        acc[g] = __builtin_amdgcn_mfma_f32_16x16x32_bf16(a, btile[g][kk], acc[g], 0, 0, 0);
    }
    if (kh == 1){
#pragma unroll
      for (int g = 0; g < 4; g++)
#pragma unroll
        for (int j = 0; j < 4; j++)
          lbuf[p][cw][g * 4 + j][lane] = acc[g][j];
    }
    __syncthreads();
    if (kh == 0){
#pragma unroll
      for (int j = 0; j < 4; j++){
        int r = row0 + q * 4 + j;
        float gi = acc[0][j] + lbuf[p][cw][0 + j][lane]  + bi;
        float gf = acc[1][j] + lbuf[p][cw][4 + j][lane]  + bf_;
        float gg = acc[2][j] + lbuf[p][cw][8 + j][lane]  + bg;
        float go = acc[3][j] + lbuf[p][cw][12 + j][lane] + bo;
        float is = sigm(gi), fs = sigm(gf), gt = tanh_fast(gg), os = sigm(go);
        float co = cx[(size_t)r * HH + hloc];
        float cyv = co * fs + is * gt;
        out[(size_t)r * HH + hloc]      = os * tanh_fast(cyv);
        out[NH + (size_t)r * HH + hloc] = cyv;
      }
    }
    p ^= 1;
  }
}

// ---------------- launch ----------------

extern "C" void kernel_launch(void* const* d_in, const int* in_sizes, int n_in,
                              void* d_out, int out_size, void* d_ws, size_t ws_size,
                              hipStream_t stream){
  const float* x     = (const float*)d_in[0];
  const float* hx    = (const float*)d_in[1];
  const float* cx    = (const float*)d_in[2];
  const int*   esrc  = (const int*)d_in[3];
  const int*   edst  = (const int*)d_in[4];
  const float* ew    = (const float*)d_in[5];
  const float* gcn_w = (const float*)d_in[6];
  const float* bias  = (const float*)d_in[7];
  const float* x2hw  = (const float*)d_in[8];
  const float* x2hb  = (const float*)d_in[9];
  const float* h2hw  = (const float*)d_in[10];
  const float* h2hb  = (const float*)d_in[11];
  const float* bn_g  = (const float*)d_in[12];
  const float* bn_b  = (const float*)d_in[13];
  const float* bn_m  = (const float*)d_in[14];
  const float* bn_v  = (const float*)d_in[15];
  float* out = (float*)d_out;

  char* w = (char*)d_ws;
  u16* support = (u16*)w; w += (((size_t)NN * HH * 2) + 255) & ~(size_t)255;
  u16* hbn     = (u16*)w; w += (((size_t)NN * HH * 2) + 255) & ~(size_t)255;
  u16* hxb     = (u16*)w; w += (((size_t)NN * HH * 2) + 255) & ~(size_t)255;
  int* counts  = (int*)w; w += (((size_t)NN * 4) + 255) & ~(size_t)255;
  int* offs    = (int*)w; w += (((size_t)NN * 4) + 255) & ~(size_t)255;
  int* cursor  = (int*)w; w += (((size_t)NN * 4) + 255) & ~(size_t)255;
  int* bsums   = (int*)w; w += (((size_t)SCAN_NB * 4) + 255) & ~(size_t)255;
  int2* esw    = (int2*)w; w += (((size_t)NE * 8) + 255) & ~(size_t)255;
  u16* wcat    = (u16*)w; w += (((size_t)512 * 256 * 2) + 255) & ~(size_t)255;
  u16* wgcn    = (u16*)w; w += (((size_t)128 * 128 * 2) + 255) & ~(size_t)255;
  float* bsum  = (float*)w; w += (((size_t)512 * 4) + 255) & ~(size_t)255;

  prep_pack<<<512, 256, 0, stream>>>(x2hw, h2hw, x2hb, h2hb, gcn_w, wcat, wgcn, bsum);
  zero_kernel<<<(NN + 255) / 256, 256, 0, stream>>>(counts, NN);
  hist_kernel<<<(NE + 255) / 256, 256, 0, stream>>>(edst, counts, NE);
  scan_bsum<<<SCAN_NB, 256, 0, stream>>>(counts, bsums, NN);
  scan_tops<<<1, 256, 0, stream>>>(bsums, SCAN_NB);
  scan_final<<<SCAN_NB, 256, 0, stream>>>(counts, bsums, offs, cursor, NN);
  scatter_kernel<<<(NE + 255) / 256, 256, 0, stream>>>(esrc, edst, ew, cursor, esw, NE);
  support_mfma<<<(NN + 63) / 64, 256, 0, stream>>>(x, wgcn, support, NN);
  agg_bn2<<<(NN + 3) / 4, 256, 0, stream>>>(support, esw, offs, counts,
                                            bias, bn_g, bn_b, bn_m, bn_v, hx, hbn, hxb, NN);
  gates_mfma5<<<256, 1024, 0, stream>>>(hbn, hxb, wcat, bsum, cx, out, NN);
}